// Round 1
// baseline (506.454 us; speedup 1.0000x reference)
//
#include <hip/hip_runtime.h>

// Problem constants (match reference)
#define BB   64
#define CCH  3
#define HH   640
#define WW   640
#define PHH  128
#define PWW  128

// Each thread: 4 consecutive x-pixels, all 3 channels.
// images layout (B,C,H,W) row-major.
__global__ __launch_bounds__(256) void patch_apply_kernel(
    const float* __restrict__ images,
    const float* __restrict__ patch,
    const float* __restrict__ angles,
    const float* __restrict__ scales,
    const float* __restrict__ ux,
    const float* __restrict__ uy,
    float* __restrict__ out)
{
    const int QW = WW / 4;                         // 160 quads per row
    int idx = blockIdx.x * blockDim.x + threadIdx.x;
    int b   = idx / (HH * QW);
    int rem = idx - b * (HH * QW);
    int y   = rem / QW;
    int x   = (rem - y * QW) * 4;

    const size_t plane = (size_t)HH * WW;
    const size_t base  = (size_t)b * CCH * plane + (size_t)y * WW + x;

    // Unconditional copy path: 3 x float4 load
    float4 v0 = *(const float4*)(images + base);
    float4 v1 = *(const float4*)(images + base + plane);
    float4 v2 = *(const float4*)(images + base + 2 * plane);

    // Per-batch params (wave-uniform, cached)
    float scale = scales[b];
    float sh  = floorf((float)PHH * scale);
    float sw  = floorf((float)PWW * scale);
    float y0f = floorf(uy[b] * ((float)HH - sh));
    float x0f = floorf(ux[b] * ((float)WW - sw));

    float yl  = (float)y - y0f;
    float xl0 = (float)x - x0f;

    bool rowv = (yl >= 0.0f) && (yl < sh);
    bool anyx = (xl0 + 3.0f >= 0.0f) && (xl0 < sw);

    if (rowv && anyx) {
        float theta = angles[b] * 0.017453292519943295f;  // deg2rad
        float si, co;
        sincosf(theta, &si, &co);
        float rh = (float)PHH / sh;
        float rw = (float)PWW / sw;
        const float cy = (PHH - 1) * 0.5f;
        const float cx = (PWW - 1) * 0.5f;

        float yr = (yl + 0.5f) * rh - 0.5f;
        float dy = yr - cy;

        #pragma unroll
        for (int j = 0; j < 4; ++j) {
            float xl = xl0 + (float)j;
            if (xl >= 0.0f && xl < sw) {
                float xr = (xl + 0.5f) * rw - 0.5f;
                float dx = xr - cx;
                // inverse rotation (match reference op order)
                float xp = co * dx + si * dy + cx;
                float yp = -si * dx + co * dy + cy;

                float yfl = floorf(yp);
                float xfl = floorf(xp);
                float wy = yp - yfl;
                float wx = xp - xfl;
                int yi = (int)yfl;
                int xi = (int)xfl;

                bool iy0 = (yi     >= 0) && (yi     <= PHH - 1);
                bool iy1 = (yi + 1 >= 0) && (yi + 1 <= PHH - 1);
                bool ix0 = (xi     >= 0) && (xi     <= PWW - 1);
                bool ix1 = (xi + 1 >= 0) && (xi + 1 <= PWW - 1);

                int yc0 = min(max(yi,     0), PHH - 1);
                int yc1 = min(max(yi + 1, 0), PHH - 1);
                int xc0 = min(max(xi,     0), PWW - 1);
                int xc1 = min(max(xi + 1, 0), PWW - 1);

                float w00 = ((1.0f - wy) * (1.0f - wx)) * ((iy0 && ix0) ? 1.0f : 0.0f);
                float w01 = ((1.0f - wy) * wx)          * ((iy0 && ix1) ? 1.0f : 0.0f);
                float w10 = (wy * (1.0f - wx))          * ((iy1 && ix0) ? 1.0f : 0.0f);
                float w11 = (wy * wx)                   * ((iy1 && ix1) ? 1.0f : 0.0f);

                int o00 = yc0 * PWW + xc0;
                int o01 = yc0 * PWW + xc1;
                int o10 = yc1 * PWW + xc0;
                int o11 = yc1 * PWW + xc1;

                #pragma unroll
                for (int c = 0; c < 3; ++c) {
                    const float* p = patch + c * (PHH * PWW);
                    float s = p[o00] * w00 + p[o01] * w01
                            + p[o10] * w10 + p[o11] * w11;
                    if (c == 0)      ((float*)&v0)[j] = s;
                    else if (c == 1) ((float*)&v1)[j] = s;
                    else             ((float*)&v2)[j] = s;
                }
            }
        }
    }

    *(float4*)(out + base)             = v0;
    *(float4*)(out + base + plane)     = v1;
    *(float4*)(out + base + 2 * plane) = v2;
}

extern "C" void kernel_launch(void* const* d_in, const int* in_sizes, int n_in,
                              void* d_out, int out_size, void* d_ws, size_t ws_size,
                              hipStream_t stream) {
    const float* images = (const float*)d_in[0];
    const float* patch  = (const float*)d_in[1];
    const float* angles = (const float*)d_in[2];
    const float* scales = (const float*)d_in[3];
    const float* ux     = (const float*)d_in[4];
    const float* uy     = (const float*)d_in[5];
    float* out = (float*)d_out;

    const int total  = BB * HH * (WW / 4);   // 6,553,600 threads
    const int block  = 256;
    const int blocks = total / block;        // 25,600
    patch_apply_kernel<<<blocks, block, 0, stream>>>(
        images, patch, angles, scales, ux, uy, out);
}